// Round 1
// baseline (854.093 us; speedup 1.0000x reference)
//
#include <hip/hip_runtime.h>
#include <stdint.h>
#include <stddef.h>

// Problem constants: B=8, N=4096, D=1024
#define D_ 1024
#define NSEQ_ 4096
#define BATCH_ 8
#define BN_ (BATCH_ * NSEQ_)

typedef __attribute__((ext_vector_type(8))) short short8;
typedef __attribute__((ext_vector_type(4))) short short4_t;
typedef __attribute__((ext_vector_type(4))) float float4_t;

__device__ __forceinline__ short f2b(float f) {  // fp32 -> bf16 bits, RNE
  union { float f; uint32_t u; } x; x.f = f;
  uint32_t r = x.u + 0x7fffu + ((x.u >> 16) & 1u);
  return (short)(r >> 16);
}
__device__ __forceinline__ float b2f(short s) {
  union { float f; uint32_t u; } x; x.u = ((uint32_t)(uint16_t)s) << 16; return x.f;
}

// async global->LDS, 16B per lane; LDS dest must be wave-uniform base + lane*16
__device__ __forceinline__ void gll16(const void* g, void* l) {
  auto gp = reinterpret_cast<const uint32_t __attribute__((address_space(1)))*>(
      reinterpret_cast<uintptr_t>(g));
  auto lp = reinterpret_cast<uint32_t __attribute__((address_space(3)))*>(
      reinterpret_cast<uintptr_t>(l));
  __builtin_amdgcn_global_load_lds(gp, lp, 16, 0, 0);
}

#define MFMA16(a, b, c) __builtin_amdgcn_mfma_f32_16x16x32_bf16(a, b, c, 0, 0, 0)

// ---------------------------------------------------------------------------
// Kernel 0: weights (D,D) fp32 -> transposed bf16 wT[e][d], 4 weights stacked
// ---------------------------------------------------------------------------
__global__ void transpose_convert_w(const float* __restrict__ w0, const float* __restrict__ w1,
                                    const float* __restrict__ w2, const float* __restrict__ w3,
                                    short* __restrict__ wT) {
  __shared__ float tile[32][33];
  const int z = blockIdx.z;
  const float* src = (z == 0) ? w0 : (z == 1) ? w1 : (z == 2) ? w2 : w3;
  short* dst = wT + (size_t)z * D_ * D_;
  const int d0 = blockIdx.y * 32, e0 = blockIdx.x * 32;
  const int tx = threadIdx.x, ty = threadIdx.y;
#pragma unroll
  for (int i = 0; i < 4; ++i) {
    int d = ty + i * 8;
    tile[d][tx] = src[(size_t)(d0 + d) * D_ + (e0 + tx)];
  }
  __syncthreads();
#pragma unroll
  for (int i = 0; i < 4; ++i) {
    int e = ty + i * 8;
    dst[(size_t)(e0 + e) * D_ + (d0 + tx)] = f2b(tile[tx][e]);
  }
}

// ---------------------------------------------------------------------------
// Kernel 1: dual-weight GEMM  C_w = x @ W_w  (w = 0,1), x fp32 (converted in
// staging), W as wT bf16 (rows=e, k=d contiguous). Block tile 128m x 64e x 2w.
// mode 0: out0 = relu(C0)*relu(C1) as bf16, natural [bn][e] layout (query)
// mode 1: out0/out1 = C0/C1 transposed -> [b][e][n] bf16 (kT/vT) + sumsq atomics
// ---------------------------------------------------------------------------
__global__ __launch_bounds__(256, 2) void gemm_x2w(
    const float* __restrict__ X,
    const short* __restrict__ W0, const short* __restrict__ W1,
    short* __restrict__ out0, short* __restrict__ out1,
    float* __restrict__ ss0, float* __restrict__ ss1, int mode) {
  __shared__ union {
    struct { short As[128 * 40]; short Bs[2 * 64 * 32]; } s;  // A padded +8; B unpadded (gll)
    short T[64 * 136];                                        // epilogue transpose buffer
  } u;

  const int t = threadIdx.x;
  const int w = t >> 6;
  const int lane = t & 63;
  const int l16 = lane & 15;
  const int quad = lane >> 4;
  const int wm = w >> 1, wn = w & 1;
  const int M0 = blockIdx.y * 128;  // row tile over B*N
  const int E0 = blockIdx.x * 64;   // col tile over D

  const float4_t fz = {0.f, 0.f, 0.f, 0.f};
  float4_t acc[2][4][2];
#pragma unroll
  for (int a = 0; a < 2; ++a)
#pragma unroll
    for (int i = 0; i < 4; ++i)
#pragma unroll
      for (int j = 0; j < 2; ++j) acc[a][i][j] = fz;

  const int arow = t >> 3;          // 0..31 (A staging row, +i*32)
  const int acol = (t & 7) * 4;     // 0..28 step 4
  const int browq = lane >> 2;      // 0..15
  const int bchunk = (lane & 3) * 8;

  for (int k0 = 0; k0 < 1024; k0 += 32) {
    // --- B staging: 2 weights x (64e x 32k) bf16 via global_load_lds ---
#pragma unroll
    for (int r = 0; r < 2; ++r) {
      const int q = w * 2 + r;                 // 0..7, wave-uniform
      const int wt = q >> 2;
      const int row = (q & 3) * 16 + browq;    // 0..63
      const short* g = (wt ? W1 : W0) + (size_t)(E0 + row) * 1024 + (k0 + bchunk);
      gll16(g, &u.s.Bs[q * 512]);
    }
    // --- A staging: 128m x 32k fp32 -> bf16 with conversion ---
#pragma unroll
    for (int i = 0; i < 4; ++i) {
      const int row = arow + i * 32;
      const float4_t xv = *(const float4_t*)&X[(size_t)(M0 + row) * 1024 + (k0 + acol)];
      short4_t p;
      p.x = f2b(xv.x); p.y = f2b(xv.y); p.z = f2b(xv.z); p.w = f2b(xv.w);
      *(short4_t*)&u.s.As[row * 40 + acol] = p;
    }
    __syncthreads();
    short8 aF[4], b0F[2], b1F[2];
#pragma unroll
    for (int i = 0; i < 4; ++i)
      aF[i] = *(const short8*)&u.s.As[(wm * 64 + i * 16 + l16) * 40 + quad * 8];
#pragma unroll
    for (int j = 0; j < 2; ++j) {
      b0F[j] = *(const short8*)&u.s.Bs[(wn * 32 + j * 16 + l16) * 32 + quad * 8];
      b1F[j] = *(const short8*)&u.s.Bs[2048 + (wn * 32 + j * 16 + l16) * 32 + quad * 8];
    }
#pragma unroll
    for (int i = 0; i < 4; ++i)
#pragma unroll
      for (int j = 0; j < 2; ++j) {
        acc[0][i][j] = MFMA16(aF[i], b0F[j], acc[0][i][j]);
        acc[1][i][j] = MFMA16(aF[i], b1F[j], acc[1][i][j]);
      }
    __syncthreads();
  }

  if (mode == 0) {
    // query = relu(qr)*relu(qi) -> bf16, [bn][e]
#pragma unroll
    for (int i = 0; i < 4; ++i) {
      const int rowb = M0 + wm * 64 + i * 16 + quad * 4;
#pragma unroll
      for (int j = 0; j < 2; ++j) {
        const int col = E0 + wn * 32 + j * 16 + l16;
#pragma unroll
        for (int rr = 0; rr < 4; ++rr) {
          float v = fmaxf(acc[0][i][j][rr], 0.f) * fmaxf(acc[1][i][j][rr], 0.f);
          out0[(size_t)(rowb + rr) * 1024 + col] = f2b(v);
        }
      }
    }
  } else {
    const int b = M0 >> 12;       // tile lies within one batch (128 | 4096)
    const int n0 = M0 & 4095;
#pragma unroll
    for (int wt = 0; wt < 2; ++wt) {
      short* dst = wt ? out1 : out0;
      float* ss = wt ? ss1 : ss0;
      __syncthreads();
      // registers -> LDS transposed: T[e_local][m_local]
#pragma unroll
      for (int i = 0; i < 4; ++i) {
        const int rowl = wm * 64 + i * 16 + quad * 4;
#pragma unroll
        for (int j = 0; j < 2; ++j) {
          const int coll = wn * 32 + j * 16 + l16;
#pragma unroll
          for (int rr = 0; rr < 4; ++rr)
            u.T[coll * 136 + rowl + rr] = f2b(acc[wt][i][j][rr]);
        }
      }
      __syncthreads();
      // drain rows of T -> global [b][e][n] (coalesced) + sumsq reduction
#pragma unroll
      for (int it = 0; it < 4; ++it) {
        const int e = it * 16 + (t >> 4);
        const int mchunk = (t & 15) * 8;
        short8 vv = *(const short8*)&u.T[e * 136 + mchunk];
        *(short8*)&dst[((size_t)b * 1024 + E0 + e) * 4096 + n0 + mchunk] = vv;
        float s = 0.f;
#pragma unroll
        for (int x2 = 0; x2 < 8; ++x2) { float f = b2f(vv[x2]); s += f * f; }
        s += __shfl_xor(s, 1, 16);
        s += __shfl_xor(s, 2, 16);
        s += __shfl_xor(s, 4, 16);
        s += __shfl_xor(s, 8, 16);
        if ((t & 15) == 0) atomicAdd(&ss[b * 1024 + E0 + e], s);
      }
    }
  }
}

// ---------------------------------------------------------------------------
// Kernel 2: inv norms: inv[i] = 1/(sqrt(ss[i]) + 1e-5), 2*B*D entries
// ---------------------------------------------------------------------------
__global__ void finish_norms(const float* __restrict__ ss, float* __restrict__ inv) {
  const int i = blockIdx.x * 256 + threadIdx.x;
  if (i < 2 * BATCH_ * D_) inv[i] = 1.f / (sqrtf(ss[i]) + 1e-5f);
}

// ---------------------------------------------------------------------------
// Kernel 3: generic batched gemm_bt: C[m][n] = sum_k A[m][k]*B[n][k], bf16 in,
// both operands row-major with k contiguous (ld == K). 128x128 tile, BK=32.
// mode 0: out bf16 = relu(C * rs[m] * cs[n])   (kv^T epilogue)
// mode 1: out fp32 = C                          (final output)
// ---------------------------------------------------------------------------
__global__ __launch_bounds__(256, 2) void gemm_bt(
    const short* __restrict__ A, const short* __restrict__ Bm,
    size_t sAb, size_t sBb, int K, int mode,
    const float* __restrict__ rsb, const float* __restrict__ csb,
    void* __restrict__ outp) {
  __shared__ short As[128 * 32];
  __shared__ short Bs[128 * 32];
  const int t = threadIdx.x;
  const int w = t >> 6;
  const int lane = t & 63;
  const int l16 = lane & 15;
  const int quad = lane >> 4;
  const int wm = w >> 1, wn = w & 1;
  const int M0 = blockIdx.y * 128, N0 = blockIdx.x * 128, b = blockIdx.z;
  const short* Ab = A + (size_t)b * sAb;
  const short* Bb = Bm + (size_t)b * sBb;

  const float4_t fz = {0.f, 0.f, 0.f, 0.f};
  float4_t acc[4][4];
#pragma unroll
  for (int i = 0; i < 4; ++i)
#pragma unroll
    for (int j = 0; j < 4; ++j) acc[i][j] = fz;

  const int rowq = lane >> 2;
  const int chunk = (lane & 3) * 8;

  for (int k0 = 0; k0 < K; k0 += 32) {
#pragma unroll
    for (int r = 0; r < 4; ++r) {
      const int q = w * 4 + r;  // 0..15, wave-uniform
      if (q < 8) {
        const int row = q * 16 + rowq;
        gll16(Ab + (size_t)(M0 + row) * K + (k0 + chunk), &As[q * 512]);
      } else {
        const int row = (q - 8) * 16 + rowq;
        gll16(Bb + (size_t)(N0 + row) * K + (k0 + chunk), &Bs[(q - 8) * 512]);
      }
    }
    __syncthreads();
    short8 aF[4], bF[4];
#pragma unroll
    for (int i = 0; i < 4; ++i)
      aF[i] = *(const short8*)&As[(wm * 64 + i * 16 + l16) * 32 + quad * 8];
#pragma unroll
    for (int j = 0; j < 4; ++j)
      bF[j] = *(const short8*)&Bs[(wn * 64 + j * 16 + l16) * 32 + quad * 8];
#pragma unroll
    for (int i = 0; i < 4; ++i)
#pragma unroll
      for (int j = 0; j < 4; ++j) acc[i][j] = MFMA16(aF[i], bF[j], acc[i][j]);
    __syncthreads();
  }

  if (mode == 0) {
    short* ob = (short*)outp + (size_t)b * D_ * D_;
    const float* rs = rsb + b * D_ + M0;
    const float* cs = csb + b * D_ + N0;
#pragma unroll
    for (int i = 0; i < 4; ++i) {
      const int rl = wm * 64 + i * 16 + quad * 4;
#pragma unroll
      for (int j = 0; j < 4; ++j) {
        const int cl = wn * 64 + j * 16 + l16;
        const float csc = cs[cl];
#pragma unroll
        for (int rr = 0; rr < 4; ++rr) {
          float v = acc[i][j][rr] * rs[rl + rr] * csc;
          v = fmaxf(v, 0.f);
          ob[(size_t)(M0 + rl + rr) * 1024 + (N0 + cl)] = f2b(v);
        }
      }
    }
  } else {
    float* of = (float*)outp + (size_t)b * NSEQ_ * D_;
#pragma unroll
    for (int i = 0; i < 4; ++i) {
      const int rl = wm * 64 + i * 16 + quad * 4;
#pragma unroll
      for (int j = 0; j < 4; ++j) {
        const int cl = wn * 64 + j * 16 + l16;
#pragma unroll
        for (int rr = 0; rr < 4; ++rr)
          of[(size_t)(M0 + rl + rr) * 1024 + (N0 + cl)] = acc[i][j][rr];
      }
    }
  }
}

// ---------------------------------------------------------------------------
extern "C" void kernel_launch(void* const* d_in, const int* in_sizes, int n_in,
                              void* d_out, int out_size, void* d_ws, size_t ws_size,
                              hipStream_t stream) {
  const float* x = (const float*)d_in[0];
  const float* wqr = (const float*)d_in[1];
  const float* wqi = (const float*)d_in[2];
  const float* wk = (const float*)d_in[3];
  const float* wv = (const float*)d_in[4];

  // workspace layout (all bf16 stored as short)
  short* wT = (short*)d_ws;                          // 4 * D*D            (8 MB)
  short* qb = wT + (size_t)4 * D_ * D_;              // BN * D             (64 MB)
  short* kT = qb + (size_t)BN_ * D_;                 // B * D * N          (64 MB)
  short* vT = kT + (size_t)BATCH_ * D_ * NSEQ_;      // B * D * N          (64 MB)
  short* kvT = vT + (size_t)BATCH_ * D_ * NSEQ_;     // B * D * D          (16 MB)
  float* ssk = (float*)(kvT + (size_t)BATCH_ * D_ * D_);  // B*D
  float* ssv = ssk + BATCH_ * D_;                    // B*D  (contiguous with ssk)
  float* invk = ssv + BATCH_ * D_;                   // B*D
  float* invv = invk + BATCH_ * D_;                  // B*D  (contiguous with invk)

  hipMemsetAsync(ssk, 0, (size_t)2 * BATCH_ * D_ * sizeof(float), stream);

  transpose_convert_w<<<dim3(32, 32, 4), dim3(32, 8), 0, stream>>>(wqr, wqi, wk, wv, wT);

  // query pair: qr,qi -> query bf16
  gemm_x2w<<<dim3(16, 256), 256, 0, stream>>>(
      x, wT, wT + (size_t)D_ * D_, qb, nullptr, nullptr, nullptr, 0);
  // key/value pair -> kT, vT (transposed) + sumsq
  gemm_x2w<<<dim3(16, 256), 256, 0, stream>>>(
      x, wT + (size_t)2 * D_ * D_, wT + (size_t)3 * D_ * D_, kT, vT, ssk, ssv, 1);

  finish_norms<<<dim3(64), 256, 0, stream>>>(ssk, invk);

  // kv^T[b][e][d] = relu( (sum_n V[n,e]K[n,d]) * invv[e] * invk[d] )
  gemm_bt<<<dim3(8, 8, 8), 256, 0, stream>>>(
      vT, kT, (size_t)D_ * NSEQ_, (size_t)D_ * NSEQ_, 4096, 0, invv, invk, (void*)kvT);

  // out[b][n][e] = sum_d query[n,d] * kv^T[e,d]   (fp32)
  gemm_bt<<<dim3(8, 32, 8), 256, 0, stream>>>(
      qb, kvT, (size_t)NSEQ_ * D_, (size_t)D_ * D_, 1024, 1, nullptr, nullptr, d_out);
}

// Round 2
// 804.072 us; speedup vs baseline: 1.0622x; 1.0622x over previous
//
#include <hip/hip_runtime.h>
#include <stdint.h>
#include <stddef.h>

// Problem constants: B=8, N=4096, D=1024
#define D_ 1024
#define NSEQ_ 4096
#define BATCH_ 8
#define BN_ (BATCH_ * NSEQ_)

typedef __attribute__((ext_vector_type(8))) short short8;
typedef __attribute__((ext_vector_type(4))) short short4_t;
typedef __attribute__((ext_vector_type(4))) float float4_t;

__device__ __forceinline__ short f2b(float f) {  // fp32 -> bf16 bits, RNE
  union { float f; uint32_t u; } x; x.f = f;
  uint32_t r = x.u + 0x7fffu + ((x.u >> 16) & 1u);
  return (short)(r >> 16);
}
__device__ __forceinline__ float b2f(short s) {
  union { float f; uint32_t u; } x; x.u = ((uint32_t)(uint16_t)s) << 16; return x.f;
}

// async global->LDS, 16B per lane; LDS dest is wave-uniform base + lane*16
__device__ __forceinline__ void gll16(const void* g, void* l) {
  auto gp = reinterpret_cast<const uint32_t __attribute__((address_space(1)))*>(
      reinterpret_cast<uintptr_t>(g));
  auto lp = reinterpret_cast<uint32_t __attribute__((address_space(3)))*>(
      reinterpret_cast<uintptr_t>(l));
  __builtin_amdgcn_global_load_lds(gp, lp, 16, 0, 0);
}

#define MFMA16(a, b, c) __builtin_amdgcn_mfma_f32_16x16x32_bf16(a, b, c, 0, 0, 0)

// ---------------------------------------------------------------------------
// Kernel A: x fp32 -> bf16 (memory-bound, 8 elems/thread)
// ---------------------------------------------------------------------------
__global__ void convert_x(const float* __restrict__ X, short* __restrict__ Xb) {
  const size_t i = (size_t)blockIdx.x * 256 + threadIdx.x;  // 8 elems each
  const float4_t* p = (const float4_t*)(X + i * 8);
  float4_t a = p[0], b = p[1];
  short8 o;
  o[0] = f2b(a.x); o[1] = f2b(a.y); o[2] = f2b(a.z); o[3] = f2b(a.w);
  o[4] = f2b(b.x); o[5] = f2b(b.y); o[6] = f2b(b.z); o[7] = f2b(b.w);
  *(short8*)(Xb + i * 8) = o;
}

// ---------------------------------------------------------------------------
// Kernel 0: weights (D,D) fp32 -> transposed bf16 wT[e][d], 4 weights stacked
// ---------------------------------------------------------------------------
__global__ void transpose_convert_w(const float* __restrict__ w0, const float* __restrict__ w1,
                                    const float* __restrict__ w2, const float* __restrict__ w3,
                                    short* __restrict__ wT) {
  __shared__ float tile[32][33];
  const int z = blockIdx.z;
  const float* src = (z == 0) ? w0 : (z == 1) ? w1 : (z == 2) ? w2 : w3;
  short* dst = wT + (size_t)z * D_ * D_;
  const int d0 = blockIdx.y * 32, e0 = blockIdx.x * 32;
  const int tx = threadIdx.x, ty = threadIdx.y;
#pragma unroll
  for (int i = 0; i < 4; ++i) {
    int d = ty + i * 8;
    tile[d][tx] = src[(size_t)(d0 + d) * D_ + (e0 + tx)];
  }
  __syncthreads();
#pragma unroll
  for (int i = 0; i < 4; ++i) {
    int e = ty + i * 8;
    dst[(size_t)(e0 + e) * D_ + (d0 + tx)] = f2b(tile[tx][e]);
  }
}

// ---------------------------------------------------------------------------
// Kernel 1: dual-weight GEMM  C_w = xb @ W_w  (w = 0,1), all-bf16, both
// operands staged via global_load_lds width-16 (m97 structure).
// Block tile 128m x 64e x 2w, BK=32.
// mode 0: out0 = relu(C0)*relu(C1) as bf16, natural [bn][e] layout (query)
// mode 1: out0/out1 = C0/C1 transposed -> [b][e][n] bf16 (kT/vT) + sumsq atomics
// ---------------------------------------------------------------------------
__global__ __launch_bounds__(256, 2) void gemm_x2w(
    const short* __restrict__ Xb,
    const short* __restrict__ W0, const short* __restrict__ W1,
    short* __restrict__ out0, short* __restrict__ out1,
    float* __restrict__ ss0, float* __restrict__ ss1, int mode) {
  __shared__ union {
    struct { short As[128 * 32]; short Bs[2 * 64 * 32]; } s;  // unpadded (gll layout)
    short T[64 * 136];                                        // epilogue transpose buffer
  } u;

  const int t = threadIdx.x;
  const int w = t >> 6;
  const int lane = t & 63;
  const int l16 = lane & 15;
  const int quad = lane >> 4;
  const int wm = w >> 1, wn = w & 1;
  const int M0 = blockIdx.y * 128;  // row tile over B*N
  const int E0 = blockIdx.x * 64;   // col tile over D

  const float4_t fz = {0.f, 0.f, 0.f, 0.f};
  float4_t acc[2][4][2];
#pragma unroll
  for (int a = 0; a < 2; ++a)
#pragma unroll
    for (int i = 0; i < 4; ++i)
#pragma unroll
      for (int j = 0; j < 2; ++j) acc[a][i][j] = fz;

  const int rowq = lane >> 2;       // 0..15
  const int chunk = (lane & 3) * 8; // k-chunk within 32

  for (int k0 = 0; k0 < 1024; k0 += 32) {
    // 16 gll units per block: 8 for A (128 rows), 8 for B (2 weights x 64 rows)
#pragma unroll
    for (int r = 0; r < 4; ++r) {
      const int q = w * 4 + r;  // 0..15, wave-uniform
      if (q < 8) {
        gll16(Xb + (size_t)(M0 + q * 16 + rowq) * 1024 + (k0 + chunk), &u.s.As[q * 512]);
      } else {
        const int qq = q - 8;
        const int wt = qq >> 2;
        const int row = (qq & 3) * 16 + rowq;
        gll16((wt ? W1 : W0) + (size_t)(E0 + row) * 1024 + (k0 + chunk),
              &u.s.Bs[qq * 512]);
      }
    }
    __syncthreads();
    short8 aF[4], b0F[2], b1F[2];
#pragma unroll
    for (int i = 0; i < 4; ++i)
      aF[i] = *(const short8*)&u.s.As[(wm * 64 + i * 16 + l16) * 32 + quad * 8];
#pragma unroll
    for (int j = 0; j < 2; ++j) {
      b0F[j] = *(const short8*)&u.s.Bs[(wn * 32 + j * 16 + l16) * 32 + quad * 8];
      b1F[j] = *(const short8*)&u.s.Bs[2048 + (wn * 32 + j * 16 + l16) * 32 + quad * 8];
    }
#pragma unroll
    for (int i = 0; i < 4; ++i)
#pragma unroll
      for (int j = 0; j < 2; ++j) {
        acc[0][i][j] = MFMA16(aF[i], b0F[j], acc[0][i][j]);
        acc[1][i][j] = MFMA16(aF[i], b1F[j], acc[1][i][j]);
      }
    __syncthreads();
  }

  if (mode == 0) {
    // query = relu(qr)*relu(qi) -> bf16, [bn][e]
#pragma unroll
    for (int i = 0; i < 4; ++i) {
      const int rowb = M0 + wm * 64 + i * 16 + quad * 4;
#pragma unroll
      for (int j = 0; j < 2; ++j) {
        const int col = E0 + wn * 32 + j * 16 + l16;
#pragma unroll
        for (int rr = 0; rr < 4; ++rr) {
          float v = fmaxf(acc[0][i][j][rr], 0.f) * fmaxf(acc[1][i][j][rr], 0.f);
          out0[(size_t)(rowb + rr) * 1024 + col] = f2b(v);
        }
      }
    }
  } else {
    const int b = M0 >> 12;       // tile lies within one batch (128 | 4096)
    const int n0 = M0 & 4095;
#pragma unroll
    for (int wt = 0; wt < 2; ++wt) {
      short* dst = wt ? out1 : out0;
      float* ss = wt ? ss1 : ss0;
      __syncthreads();
      // registers -> LDS transposed: T[e_local][m_local]
#pragma unroll
      for (int i = 0; i < 4; ++i) {
        const int rowl = wm * 64 + i * 16 + quad * 4;
#pragma unroll
        for (int j = 0; j < 2; ++j) {
          const int coll = wn * 32 + j * 16 + l16;
#pragma unroll
          for (int rr = 0; rr < 4; ++rr)
            u.T[coll * 136 + rowl + rr] = f2b(acc[wt][i][j][rr]);
        }
      }
      __syncthreads();
      // drain rows of T -> global [b][e][n] (coalesced) + sumsq reduction
#pragma unroll
      for (int it = 0; it < 4; ++it) {
        const int e = it * 16 + (t >> 4);
        const int mchunk = (t & 15) * 8;
        short8 vv = *(const short8*)&u.T[e * 136 + mchunk];
        *(short8*)&dst[((size_t)b * 1024 + E0 + e) * 4096 + n0 + mchunk] = vv;
        float s = 0.f;
#pragma unroll
        for (int x2 = 0; x2 < 8; ++x2) { float f = b2f(vv[x2]); s += f * f; }
        s += __shfl_xor(s, 1, 16);
        s += __shfl_xor(s, 2, 16);
        s += __shfl_xor(s, 4, 16);
        s += __shfl_xor(s, 8, 16);
        if ((t & 15) == 0) atomicAdd(&ss[b * 1024 + E0 + e], s);
      }
    }
  }
}

// ---------------------------------------------------------------------------
// Kernel 2: inv norms: inv[i] = 1/(sqrt(ss[i]) + 1e-5), 2*B*D entries
// ---------------------------------------------------------------------------
__global__ void finish_norms(const float* __restrict__ ss, float* __restrict__ inv) {
  const int i = blockIdx.x * 256 + threadIdx.x;
  if (i < 2 * BATCH_ * D_) inv[i] = 1.f / (sqrtf(ss[i]) + 1e-5f);
}

// ---------------------------------------------------------------------------
// Kernel 3: generic batched gemm_bt: C[m][n] = sum_k A[m][k]*B[n][k], bf16 in,
// both operands row-major with k contiguous (ld == K). 128x128 tile, BK=32.
// mode 0: out bf16 = relu(C * rs[m] * cs[n])   (kv^T epilogue)
// mode 1: out fp32 = C                          (final output)
// ---------------------------------------------------------------------------
__global__ __launch_bounds__(256, 2) void gemm_bt(
    const short* __restrict__ A, const short* __restrict__ Bm,
    size_t sAb, size_t sBb, int K, int mode,
    const float* __restrict__ rsb, const float* __restrict__ csb,
    void* __restrict__ outp) {
  __shared__ short As[128 * 32];
  __shared__ short Bs[128 * 32];
  const int t = threadIdx.x;
  const int w = t >> 6;
  const int lane = t & 63;
  const int l16 = lane & 15;
  const int quad = lane >> 4;
  const int wm = w >> 1, wn = w & 1;
  const int M0 = blockIdx.y * 128, N0 = blockIdx.x * 128, b = blockIdx.z;
  const short* Ab = A + (size_t)b * sAb;
  const short* Bb = Bm + (size_t)b * sBb;

  const float4_t fz = {0.f, 0.f, 0.f, 0.f};
  float4_t acc[4][4];
#pragma unroll
  for (int i = 0; i < 4; ++i)
#pragma unroll
    for (int j = 0; j < 4; ++j) acc[i][j] = fz;

  const int rowq = lane >> 2;
  const int chunk = (lane & 3) * 8;

  for (int k0 = 0; k0 < K; k0 += 32) {
#pragma unroll
    for (int r = 0; r < 4; ++r) {
      const int q = w * 4 + r;  // 0..15, wave-uniform
      if (q < 8) {
        const int row = q * 16 + rowq;
        gll16(Ab + (size_t)(M0 + row) * K + (k0 + chunk), &As[q * 512]);
      } else {
        const int row = (q - 8) * 16 + rowq;
        gll16(Bb + (size_t)(N0 + row) * K + (k0 + chunk), &Bs[(q - 8) * 512]);
      }
    }
    __syncthreads();
    short8 aF[4], bF[4];
#pragma unroll
    for (int i = 0; i < 4; ++i)
      aF[i] = *(const short8*)&As[(wm * 64 + i * 16 + l16) * 32 + quad * 8];
#pragma unroll
    for (int j = 0; j < 4; ++j)
      bF[j] = *(const short8*)&Bs[(wn * 64 + j * 16 + l16) * 32 + quad * 8];
#pragma unroll
    for (int i = 0; i < 4; ++i)
#pragma unroll
      for (int j = 0; j < 4; ++j) acc[i][j] = MFMA16(aF[i], bF[j], acc[i][j]);
    __syncthreads();
  }

  if (mode == 0) {
    short* ob = (short*)outp + (size_t)b * D_ * D_;
    const float* rs = rsb + b * D_ + M0;
    const float* cs = csb + b * D_ + N0;
#pragma unroll
    for (int i = 0; i < 4; ++i) {
      const int rl = wm * 64 + i * 16 + quad * 4;
#pragma unroll
      for (int j = 0; j < 4; ++j) {
        const int cl = wn * 64 + j * 16 + l16;
        const float csc = cs[cl];
#pragma unroll
        for (int rr = 0; rr < 4; ++rr) {
          float v = acc[i][j][rr] * rs[rl + rr] * csc;
          v = fmaxf(v, 0.f);
          ob[(size_t)(M0 + rl + rr) * 1024 + (N0 + cl)] = f2b(v);
        }
      }
    }
  } else {
    float* of = (float*)outp + (size_t)b * NSEQ_ * D_;
#pragma unroll
    for (int i = 0; i < 4; ++i) {
      const int rl = wm * 64 + i * 16 + quad * 4;
#pragma unroll
      for (int j = 0; j < 4; ++j) {
        const int cl = wn * 64 + j * 16 + l16;
#pragma unroll
        for (int rr = 0; rr < 4; ++rr)
          of[(size_t)(M0 + rl + rr) * 1024 + (N0 + cl)] = acc[i][j][rr];
      }
    }
  }
}

// ---------------------------------------------------------------------------
extern "C" void kernel_launch(void* const* d_in, const int* in_sizes, int n_in,
                              void* d_out, int out_size, void* d_ws, size_t ws_size,
                              hipStream_t stream) {
  const float* x = (const float*)d_in[0];
  const float* wqr = (const float*)d_in[1];
  const float* wqi = (const float*)d_in[2];
  const float* wk = (const float*)d_in[3];
  const float* wv = (const float*)d_in[4];

  // workspace layout (all bf16 stored as short)
  short* wT = (short*)d_ws;                          // 4 * D*D            (8 MB)
  short* qb = wT + (size_t)4 * D_ * D_;              // BN * D             (64 MB)
  short* kT = qb + (size_t)BN_ * D_;                 // B * D * N          (64 MB)
  short* vT = kT + (size_t)BATCH_ * D_ * NSEQ_;      // B * D * N          (64 MB)
  short* kvT = vT + (size_t)BATCH_ * D_ * NSEQ_;     // B * D * D          (16 MB)
  float* ssk = (float*)(kvT + (size_t)BATCH_ * D_ * D_);  // B*D
  float* ssv = ssk + BATCH_ * D_;                    // B*D  (contiguous with ssk)
  float* invk = ssv + BATCH_ * D_;                   // B*D
  float* invv = invk + BATCH_ * D_;                  // B*D  (contiguous with invk)

  // bf16 x parked in d_out (128 MB fp32 buffer; only written by the final
  // GEMM, which runs strictly after x's last use)
  short* xb = (short*)d_out;

  hipMemsetAsync(ssk, 0, (size_t)2 * BATCH_ * D_ * sizeof(float), stream);

  // x fp32 -> bf16 : 33.5M elems / 8 per thread / 256 per block
  convert_x<<<dim3(16384), 256, 0, stream>>>(x, xb);

  transpose_convert_w<<<dim3(32, 32, 4), dim3(32, 8), 0, stream>>>(wqr, wqi, wk, wv, wT);

  // query pair: qr,qi -> query bf16
  gemm_x2w<<<dim3(16, 256), 256, 0, stream>>>(
      xb, wT, wT + (size_t)D_ * D_, qb, nullptr, nullptr, nullptr, 0);
  // key/value pair -> kT, vT (transposed) + sumsq
  gemm_x2w<<<dim3(16, 256), 256, 0, stream>>>(
      xb, wT + (size_t)2 * D_ * D_, wT + (size_t)3 * D_ * D_, kT, vT, ssk, ssv, 1);

  finish_norms<<<dim3(64), 256, 0, stream>>>(ssk, invk);

  // kv^T[b][e][d] = relu( (sum_n V[n,e]K[n,d]) * invv[e] * invk[d] )
  gemm_bt<<<dim3(8, 8, 8), 256, 0, stream>>>(
      vT, kT, (size_t)D_ * NSEQ_, (size_t)D_ * NSEQ_, 4096, 0, invv, invk, (void*)kvT);

  // out[b][n][e] = sum_d query[n,d] * kv^T[e,d]   (fp32)
  gemm_bt<<<dim3(8, 32, 8), 256, 0, stream>>>(
      qb, kvT, (size_t)NSEQ_ * D_, (size_t)D_ * D_, 1024, 1, nullptr, nullptr, d_out);
}

// Round 3
// 777.137 us; speedup vs baseline: 1.0990x; 1.0347x over previous
//
#include <hip/hip_runtime.h>
#include <stdint.h>
#include <stddef.h>

// Problem constants: B=8, N=4096, D=1024
#define D_ 1024
#define NSEQ_ 4096
#define BATCH_ 8
#define BN_ (BATCH_ * NSEQ_)

typedef __attribute__((ext_vector_type(8))) short short8;
typedef __attribute__((ext_vector_type(4))) short short4_t;
typedef __attribute__((ext_vector_type(4))) float float4_t;

__device__ __forceinline__ short f2b(float f) {  // fp32 -> bf16 bits, RNE
  union { float f; uint32_t u; } x; x.f = f;
  uint32_t r = x.u + 0x7fffu + ((x.u >> 16) & 1u);
  return (short)(r >> 16);
}
__device__ __forceinline__ float b2f(short s) {
  union { float f; uint32_t u; } x; x.u = ((uint32_t)(uint16_t)s) << 16; return x.f;
}

// async global->LDS, 16B per lane; LDS dest is wave-uniform base + lane*16
__device__ __forceinline__ void gll16(const void* g, void* l) {
  auto gp = reinterpret_cast<const uint32_t __attribute__((address_space(1)))*>(
      reinterpret_cast<uintptr_t>(g));
  auto lp = reinterpret_cast<uint32_t __attribute__((address_space(3)))*>(
      reinterpret_cast<uintptr_t>(l));
  __builtin_amdgcn_global_load_lds(gp, lp, 16, 0, 0);
}

#define MFMA16(a, b, c) __builtin_amdgcn_mfma_f32_16x16x32_bf16(a, b, c, 0, 0, 0)

// ---------------------------------------------------------------------------
// Kernel A: x fp32 -> bf16 (memory-bound, 8 elems/thread)
// ---------------------------------------------------------------------------
__global__ void convert_x(const float* __restrict__ X, short* __restrict__ Xb) {
  const size_t i = (size_t)blockIdx.x * 256 + threadIdx.x;  // 8 elems each
  const float4_t* p = (const float4_t*)(X + i * 8);
  float4_t a = p[0], b = p[1];
  short8 o;
  o[0] = f2b(a.x); o[1] = f2b(a.y); o[2] = f2b(a.z); o[3] = f2b(a.w);
  o[4] = f2b(b.x); o[5] = f2b(b.y); o[6] = f2b(b.z); o[7] = f2b(b.w);
  *(short8*)(Xb + i * 8) = o;
}

// ---------------------------------------------------------------------------
// Kernel 0: weights (D,D) fp32 -> transposed bf16 wT[e][d], 4 weights stacked
// ---------------------------------------------------------------------------
__global__ void transpose_convert_w(const float* __restrict__ w0, const float* __restrict__ w1,
                                    const float* __restrict__ w2, const float* __restrict__ w3,
                                    short* __restrict__ wT) {
  __shared__ float tile[32][33];
  const int z = blockIdx.z;
  const float* src = (z == 0) ? w0 : (z == 1) ? w1 : (z == 2) ? w2 : w3;
  short* dst = wT + (size_t)z * D_ * D_;
  const int d0 = blockIdx.y * 32, e0 = blockIdx.x * 32;
  const int tx = threadIdx.x, ty = threadIdx.y;
#pragma unroll
  for (int i = 0; i < 4; ++i) {
    int d = ty + i * 8;
    tile[d][tx] = src[(size_t)(d0 + d) * D_ + (e0 + tx)];
  }
  __syncthreads();
#pragma unroll
  for (int i = 0; i < 4; ++i) {
    int e = ty + i * 8;
    dst[(size_t)(e0 + e) * D_ + (d0 + tx)] = f2b(tile[tx][e]);
  }
}

// ---------------------------------------------------------------------------
// Kernel 1: QUAD-weight GEMM  C_w = xb @ W_w  (w = 0..3), all-bf16, both
// operands staged via global_load_lds width-16. A (x) is staged and LDS-read
// ONCE for all 4 weights: per block-k-step 24 KB staged / 128 MFMA (vs
// 2x16KB/64 in the dual version).
// Block tile 128m x 64e x 4w, BK=32.
// Epilogue: w0,w1 -> query = relu*relu, bf16 [bn][e]
//           w2,w3 -> kT,vT transposed [b][e][n] bf16 + sumsq atomics
// ---------------------------------------------------------------------------
__global__ __launch_bounds__(256, 2) void gemm_x4w(
    const short* __restrict__ Xb, const short* __restrict__ Wall,
    short* __restrict__ qout, short* __restrict__ kT, short* __restrict__ vT,
    float* __restrict__ ssk, float* __restrict__ ssv) {
  __shared__ union {
    struct { short As[128 * 32]; short Bs[4 * 64 * 32]; } s;  // 8 KB + 16 KB
    short T[64 * 136];                                        // epilogue transpose
  } u;

  const int t = threadIdx.x;
  const int w = t >> 6;
  const int lane = t & 63;
  const int l16 = lane & 15;
  const int quad = lane >> 4;
  const int wm = w >> 1, wn = w & 1;
  const int M0 = blockIdx.y * 128;  // row tile over B*N
  const int E0 = blockIdx.x * 64;   // col tile over D

  const float4_t fz = {0.f, 0.f, 0.f, 0.f};
  float4_t acc[4][4][2];  // [weight][i][j] = 32 float4 = 128 acc regs
#pragma unroll
  for (int a = 0; a < 4; ++a)
#pragma unroll
    for (int i = 0; i < 4; ++i)
#pragma unroll
      for (int j = 0; j < 2; ++j) acc[a][i][j] = fz;

  const int rowq = lane >> 2;       // 0..15
  const int chunk = (lane & 3) * 8; // k-chunk within 32

  for (int k0 = 0; k0 < 1024; k0 += 32) {
    // 24 gll units: 8 for A (128 rows), 16 for B (4 weights x 64 rows)
#pragma unroll
    for (int r = 0; r < 6; ++r) {
      const int q = w * 6 + r;  // 0..23, wave-uniform
      if (q < 8) {
        gll16(Xb + (size_t)(M0 + q * 16 + rowq) * 1024 + (k0 + chunk), &u.s.As[q * 512]);
      } else {
        const int qq = q - 8;  // 0..15: weight qq>>2, row-block qq&3
        gll16(Wall + (size_t)(qq >> 2) * D_ * D_ +
                  (size_t)(E0 + (qq & 3) * 16 + rowq) * 1024 + (k0 + chunk),
              &u.s.Bs[qq * 512]);
      }
    }
    __syncthreads();
    short8 aF[4], bF[4][2];
#pragma unroll
    for (int i = 0; i < 4; ++i)
      aF[i] = *(const short8*)&u.s.As[(wm * 64 + i * 16 + l16) * 32 + quad * 8];
#pragma unroll
    for (int wt = 0; wt < 4; ++wt)
#pragma unroll
      for (int j = 0; j < 2; ++j)
        bF[wt][j] = *(const short8*)&u.s.Bs[wt * 2048 + (wn * 32 + j * 16 + l16) * 32 + quad * 8];
#pragma unroll
    for (int i = 0; i < 4; ++i)
#pragma unroll
      for (int wt = 0; wt < 4; ++wt)
#pragma unroll
        for (int j = 0; j < 2; ++j)
          acc[wt][i][j] = MFMA16(aF[i], bF[wt][j], acc[wt][i][j]);
    __syncthreads();
  }

  // --- epilogue 1: query = relu(qr)*relu(qi) -> bf16, [bn][e] (no LDS) ---
#pragma unroll
  for (int i = 0; i < 4; ++i) {
    const int rowb = M0 + wm * 64 + i * 16 + quad * 4;
#pragma unroll
    for (int j = 0; j < 2; ++j) {
      const int col = E0 + wn * 32 + j * 16 + l16;
#pragma unroll
      for (int rr = 0; rr < 4; ++rr) {
        float v = fmaxf(acc[0][i][j][rr], 0.f) * fmaxf(acc[1][i][j][rr], 0.f);
        qout[(size_t)(rowb + rr) * 1024 + col] = f2b(v);
      }
    }
  }

  // --- epilogue 2: k,v transposed -> [b][e][n] + sumsq ---
  const int b = M0 >> 12;       // tile lies within one batch (128 | 4096)
  const int n0 = M0 & 4095;
#pragma unroll
  for (int wt = 2; wt < 4; ++wt) {
    short* dst = (wt == 2) ? kT : vT;
    float* ss = (wt == 2) ? ssk : ssv;
    if (wt == 3) __syncthreads();  // protect T from previous drain
    // registers -> LDS transposed: T[e_local][m_local]
#pragma unroll
    for (int i = 0; i < 4; ++i) {
      const int rowl = wm * 64 + i * 16 + quad * 4;
#pragma unroll
      for (int j = 0; j < 2; ++j) {
        const int coll = wn * 32 + j * 16 + l16;
#pragma unroll
        for (int rr = 0; rr < 4; ++rr)
          u.T[coll * 136 + rowl + rr] = f2b(acc[wt][i][j][rr]);
      }
    }
    __syncthreads();
    // drain rows of T -> global [b][e][n] (coalesced) + sumsq reduction
#pragma unroll
    for (int it = 0; it < 4; ++it) {
      const int e = it * 16 + (t >> 4);
      const int mchunk = (t & 15) * 8;
      short8 vv = *(const short8*)&u.T[e * 136 + mchunk];
      *(short8*)&dst[((size_t)b * 1024 + E0 + e) * 4096 + n0 + mchunk] = vv;
      float s = 0.f;
#pragma unroll
      for (int x2 = 0; x2 < 8; ++x2) { float f = b2f(vv[x2]); s += f * f; }
      s += __shfl_xor(s, 1, 16);
      s += __shfl_xor(s, 2, 16);
      s += __shfl_xor(s, 4, 16);
      s += __shfl_xor(s, 8, 16);
      if ((t & 15) == 0) atomicAdd(&ss[b * 1024 + E0 + e], s);
    }
  }
}

// ---------------------------------------------------------------------------
// Kernel 2: inv norms: inv[i] = 1/(sqrt(ss[i]) + 1e-5), 2*B*D entries
// ---------------------------------------------------------------------------
__global__ void finish_norms(const float* __restrict__ ss, float* __restrict__ inv) {
  const int i = blockIdx.x * 256 + threadIdx.x;
  if (i < 2 * BATCH_ * D_) inv[i] = 1.f / (sqrtf(ss[i]) + 1e-5f);
}

// ---------------------------------------------------------------------------
// Kernel 3: generic batched gemm_bt: C[m][n] = sum_k A[m][k]*B[n][k], bf16 in,
// both operands row-major with k contiguous (ld == K). 128x128 tile, BK=32.
// mode 0: out bf16 = relu(C * rs[m] * cs[n])   (kv^T epilogue)
// mode 1: out fp32 = C                          (final output)
// ---------------------------------------------------------------------------
__global__ __launch_bounds__(256, 2) void gemm_bt(
    const short* __restrict__ A, const short* __restrict__ Bm,
    size_t sAb, size_t sBb, int K, int mode,
    const float* __restrict__ rsb, const float* __restrict__ csb,
    void* __restrict__ outp) {
  __shared__ short As[128 * 32];
  __shared__ short Bs[128 * 32];
  const int t = threadIdx.x;
  const int w = t >> 6;
  const int lane = t & 63;
  const int l16 = lane & 15;
  const int quad = lane >> 4;
  const int wm = w >> 1, wn = w & 1;
  const int M0 = blockIdx.y * 128, N0 = blockIdx.x * 128, b = blockIdx.z;
  const short* Ab = A + (size_t)b * sAb;
  const short* Bb = Bm + (size_t)b * sBb;

  const float4_t fz = {0.f, 0.f, 0.f, 0.f};
  float4_t acc[4][4];
#pragma unroll
  for (int i = 0; i < 4; ++i)
#pragma unroll
    for (int j = 0; j < 4; ++j) acc[i][j] = fz;

  const int rowq = lane >> 2;
  const int chunk = (lane & 3) * 8;

  for (int k0 = 0; k0 < K; k0 += 32) {
#pragma unroll
    for (int r = 0; r < 4; ++r) {
      const int q = w * 4 + r;  // 0..15, wave-uniform
      if (q < 8) {
        const int row = q * 16 + rowq;
        gll16(Ab + (size_t)(M0 + row) * K + (k0 + chunk), &As[q * 512]);
      } else {
        const int row = (q - 8) * 16 + rowq;
        gll16(Bb + (size_t)(N0 + row) * K + (k0 + chunk), &Bs[(q - 8) * 512]);
      }
    }
    __syncthreads();
    short8 aF[4], bF[4];
#pragma unroll
    for (int i = 0; i < 4; ++i)
      aF[i] = *(const short8*)&As[(wm * 64 + i * 16 + l16) * 32 + quad * 8];
#pragma unroll
    for (int j = 0; j < 4; ++j)
      bF[j] = *(const short8*)&Bs[(wn * 64 + j * 16 + l16) * 32 + quad * 8];
#pragma unroll
    for (int i = 0; i < 4; ++i)
#pragma unroll
      for (int j = 0; j < 4; ++j) acc[i][j] = MFMA16(aF[i], bF[j], acc[i][j]);
    __syncthreads();
  }

  if (mode == 0) {
    short* ob = (short*)outp + (size_t)b * D_ * D_;
    const float* rs = rsb + b * D_ + M0;
    const float* cs = csb + b * D_ + N0;
#pragma unroll
    for (int i = 0; i < 4; ++i) {
      const int rl = wm * 64 + i * 16 + quad * 4;
#pragma unroll
      for (int j = 0; j < 4; ++j) {
        const int cl = wn * 64 + j * 16 + l16;
        const float csc = cs[cl];
#pragma unroll
        for (int rr = 0; rr < 4; ++rr) {
          float v = acc[i][j][rr] * rs[rl + rr] * csc;
          v = fmaxf(v, 0.f);
          ob[(size_t)(M0 + rl + rr) * 1024 + (N0 + cl)] = f2b(v);
        }
      }
    }
  } else {
    float* of = (float*)outp + (size_t)b * NSEQ_ * D_;
#pragma unroll
    for (int i = 0; i < 4; ++i) {
      const int rl = wm * 64 + i * 16 + quad * 4;
#pragma unroll
      for (int j = 0; j < 4; ++j) {
        const int cl = wn * 64 + j * 16 + l16;
#pragma unroll
        for (int rr = 0; rr < 4; ++rr)
          of[(size_t)(M0 + rl + rr) * 1024 + (N0 + cl)] = acc[i][j][rr];
      }
    }
  }
}

// ---------------------------------------------------------------------------
extern "C" void kernel_launch(void* const* d_in, const int* in_sizes, int n_in,
                              void* d_out, int out_size, void* d_ws, size_t ws_size,
                              hipStream_t stream) {
  const float* x = (const float*)d_in[0];
  const float* wqr = (const float*)d_in[1];
  const float* wqi = (const float*)d_in[2];
  const float* wk = (const float*)d_in[3];
  const float* wv = (const float*)d_in[4];

  // workspace layout (all bf16 stored as short)
  short* wT = (short*)d_ws;                          // 4 * D*D            (8 MB)
  short* qb = wT + (size_t)4 * D_ * D_;              // BN * D             (64 MB)
  short* kT = qb + (size_t)BN_ * D_;                 // B * D * N          (64 MB)
  short* vT = kT + (size_t)BATCH_ * D_ * NSEQ_;      // B * D * N          (64 MB)
  short* kvT = vT + (size_t)BATCH_ * D_ * NSEQ_;     // B * D * D          (16 MB)
  float* ssk = (float*)(kvT + (size_t)BATCH_ * D_ * D_);  // B*D
  float* ssv = ssk + BATCH_ * D_;                    // B*D  (contiguous with ssk)
  float* invk = ssv + BATCH_ * D_;                   // B*D
  float* invv = invk + BATCH_ * D_;                  // B*D  (contiguous with invk)

  // bf16 x parked in d_out (128 MB fp32 buffer; only written by the final
  // GEMM, which runs strictly after x's last use)
  short* xb = (short*)d_out;

  hipMemsetAsync(ssk, 0, (size_t)2 * BATCH_ * D_ * sizeof(float), stream);

  // x fp32 -> bf16 : 33.5M elems / 8 per thread / 256 per block
  convert_x<<<dim3(16384), 256, 0, stream>>>(x, xb);

  transpose_convert_w<<<dim3(32, 32, 4), dim3(32, 8), 0, stream>>>(wqr, wqi, wk, wv, wT);

  // all four x@W GEMMs in one dispatch (A staged once for 4 weights)
  gemm_x4w<<<dim3(16, 256), 256, 0, stream>>>(xb, wT, qb, kT, vT, ssk, ssv);

  finish_norms<<<dim3(64), 256, 0, stream>>>(ssk, invk);

  // kv^T[b][e][d] = relu( (sum_n V[n,e]K[n,d]) * invv[e] * invk[d] )
  gemm_bt<<<dim3(8, 8, 8), 256, 0, stream>>>(
      vT, kT, (size_t)D_ * NSEQ_, (size_t)D_ * NSEQ_, 4096, 0, invv, invk, (void*)kvT);

  // out[b][n][e] = sum_d query[n,d] * kv^T[e,d]   (fp32)
  gemm_bt<<<dim3(8, 32, 8), 256, 0, stream>>>(
      qb, kvT, (size_t)NSEQ_ * D_, (size_t)D_ * D_, 1024, 1, nullptr, nullptr, d_out);
}